// Round 18
// baseline (519.528 us; speedup 1.0000x reference)
//
#include <hip/hip_runtime.h>
#include <cstdint>
#include <cstddef>

#define BTOT   16384
#define TSTEPS 60
#define HDIM   100
#define GDIM   400
#define NB     64
#define NTHR   1024   // 16 waves

static_assert(BTOT % NB == 0, "batch tiling");
static_assert(TSTEPS % 2 == 0, "t-loop unrolled by 2");

typedef __attribute__((ext_vector_type(8))) short bf16x8;
typedef __attribute__((ext_vector_type(4))) float f32x4;
typedef __attribute__((ext_vector_type(4))) unsigned int u32x4;

struct TFPair { uint32_t a, b; };

__host__ __device__ constexpr uint32_t rotl32c(uint32_t v, int r){
  return (v << r) | (v >> (32 - r));
}

// Threefry-2x32, 20 rounds, exactly as jax/_src/prng.py
__host__ __device__ constexpr TFPair tf2x32(uint32_t k0, uint32_t k1,
                                            uint32_t x0, uint32_t x1){
  const uint32_t ks2 = k0 ^ k1 ^ 0x1BD11BDAu;
  x0 += k0; x1 += k1;
  x0 += x1; x1 = rotl32c(x1,13); x1 ^= x0;
  x0 += x1; x1 = rotl32c(x1,15); x1 ^= x0;
  x0 += x1; x1 = rotl32c(x1,26); x1 ^= x0;
  x0 += x1; x1 = rotl32c(x1, 6); x1 ^= x0;
  x0 += k1;  x1 += ks2 + 1u;
  x0 += x1; x1 = rotl32c(x1,17); x1 ^= x0;
  x0 += x1; x1 = rotl32c(x1,29); x1 ^= x0;
  x0 += x1; x1 = rotl32c(x1,16); x1 ^= x0;
  x0 += x1; x1 = rotl32c(x1,24); x1 ^= x0;
  x0 += ks2; x1 += k0 + 2u;
  x0 += x1; x1 = rotl32c(x1,13); x1 ^= x0;
  x0 += x1; x1 = rotl32c(x1,15); x1 ^= x0;
  x0 += x1; x1 = rotl32c(x1,26); x1 ^= x0;
  x0 += x1; x1 = rotl32c(x1, 6); x1 ^= x0;
  x0 += k0;  x1 += k1 + 3u;
  x0 += x1; x1 = rotl32c(x1,17); x1 ^= x0;
  x0 += x1; x1 = rotl32c(x1,29); x1 ^= x0;
  x0 += x1; x1 = rotl32c(x1,16); x1 ^= x0;
  x0 += x1; x1 = rotl32c(x1,24); x1 ^= x0;
  x0 += k1;  x1 += ks2 + 4u;
  x0 += x1; x1 = rotl32c(x1,13); x1 ^= x0;
  x0 += x1; x1 = rotl32c(x1,15); x1 ^= x0;
  x0 += x1; x1 = rotl32c(x1,26); x1 ^= x0;
  x0 += x1; x1 = rotl32c(x1, 6); x1 ^= x0;
  x0 += ks2; x1 += k0 + 5u;
  return TFPair{x0, x1};
}

constexpr TFPair KF = tf2x32(0u, 42u, 0u, 0u);   // fold_in(key(42), 0)
constexpr TFPair KM = tf2x32(0u, 42u, 0u, 1u);   // fold_in(key(42), 1)

__device__ __forceinline__ float rcp_fast(float x){ return __builtin_amdgcn_rcpf(x); }
__device__ __forceinline__ float sigmoid_f(float x){ return rcp_fast(1.f + __expf(-x)); }
__device__ __forceinline__ float tanh_f(float x){
  float e = __expf(2.f * x);
  return 1.f - 2.f * rcp_fast(e + 1.f);
}

// jax.random.normal under threefry_partitionable: bits(n) = w0^w1 of tf(key,(0,n))
__device__ __forceinline__ float tf_noise(uint32_t k0, uint32_t k1, uint32_t n){
  TFPair r = tf2x32(k0, k1, 0u, n);
  uint32_t bits = r.a ^ r.b;
  float u = __uint_as_float((bits >> 9) | 0x3f800000u) - 1.0f;   // [0,1)
  const float LOV = -0.99999994f;                                // nextafter(-1,0)
  float v = fmaxf(LOV, fmaf(u, 2.0f, LOV));
  float w = -log1pf(-v * v);
  float p;
  if (w < 5.0f){
    w -= 2.5f;
    p =              2.81022636e-08f;
    p = fmaf(p, w,   3.43273939e-07f);
    p = fmaf(p, w,  -3.5233877e-06f);
    p = fmaf(p, w,  -4.39150654e-06f);
    p = fmaf(p, w,   0.00021858087f);
    p = fmaf(p, w,  -0.00125372503f);
    p = fmaf(p, w,  -0.00417768164f);
    p = fmaf(p, w,   0.246640727f);
    p = fmaf(p, w,   1.50140941f);
  } else {
    w = sqrtf(w) - 3.0f;
    p =             -0.000200214257f;
    p = fmaf(p, w,   0.000100950558f);
    p = fmaf(p, w,   0.00134934322f);
    p = fmaf(p, w,  -0.00367342844f);
    p = fmaf(p, w,   0.00573950773f);
    p = fmaf(p, w,  -0.0076224613f);
    p = fmaf(p, w,   0.00943887047f);
    p = fmaf(p, w,   1.00167406f);
    p = fmaf(p, w,   2.83297682f);
  }
  return 0.70710678f * (p * v);
}

__device__ __forceinline__ float idm_act(float vel, float dv, float dx,
                                         float v0, float tg, float jx,
                                         float am, float an){
  dx = fminf(fmaxf(dx, 0.5f), 1000.0f);
  float gap = jx + fmaxf(0.0f, tg*vel + vel*dv / (2.0f * sqrtf(am*an)));
  float r  = vel / v0;  float r2 = r*r;
  float gd = gap / dx;
  float a  = am * (1.0f - r2*r2 - gd*gd);
  return fminf(fmaxf(a, -3.0f), 3.0f);
}

// ---- bf16 split helpers (RNE) ----
__device__ __forceinline__ unsigned short f2bf(float f){
  uint32_t x = __float_as_uint(f);
  return (unsigned short)((x + 0x7fffu + ((x >> 16) & 1u)) >> 16);
}
__device__ __forceinline__ float bf2f(unsigned short h){
  return __uint_as_float(((uint32_t)h) << 16);
}

// Permuted z column zp = c*4 + gate <-> orig = gate*100 + c.  K = 128 (4 kf), k>=100 zero.
// A-frag (16x16x32): packet p = (mt*4 + kf)*64 + lane; lane l -> zrow = mt*16 + (l&15),
// k = kf*32 + (l>>4)*8 + j.
// ws halfword layout: [0,51200) Wh-hi   [51200,102400) Wi-hi   [102400,153600) Wi-lo
#define FRG_PACKETS (25*4*64)     // 6400
#define WS_WI_HI 51200
#define WS_WI_LO 102400
#define WHF_HW   51200            // Wh-hi frags: 102.4 KB

__global__ void build_frags_kernel(const float* __restrict__ Wi,
                                   const float* __restrict__ Wh,
                                   unsigned short* __restrict__ ws){
  int p = blockIdx.x * 256 + threadIdx.x;
  if (p >= FRG_PACKETS) return;
  int lane = p & 63;
  int kf   = (p >> 6) & 3;
  int mt   = p >> 8;
  int zc   = mt*16 + (lane & 15);             // permuted column
  int orig = (zc & 3)*100 + (zc >> 2);        // gate*100 + c
  int kb   = kf*32 + ((lane >> 4) << 3);
  #pragma unroll
  for (int j = 0; j < 8; ++j){
    int k = kb + j;
    float vh = (k < HDIM) ? Wh[(size_t)k*GDIM + orig] : 0.f;
    float vi = (k < HDIM) ? Wi[(size_t)k*GDIM + orig] : 0.f;
    unsigned short ih = f2bf(vi);
    ws[p*8 + j]            = f2bf(vh);               // Wh-hi (lo dropped)
    ws[WS_WI_HI + p*8 + j] = ih;                     // Wi-hi
    ws[WS_WI_LO + p*8 + j] = f2bf(vi - bf2f(ih));    // Wi-lo
  }
}

// h-frag LDS: hl dimension = ping-pong buffer in steady state (hl1 = proj-lo at init)
#define HBF_HW (2*4*4*512)   // 16384 hw = 32 KB
__device__ __forceinline__ int hfr_idx(int hl, int bt, int kf, int lp, int j){
  return (((hl*4 + bt)*4 + kf)*512 + lp*8 + j);
}

// steady-state SINGLE-pass: acc += Wh_hi * h_bf16, B from hbf buffer CUR (compile-time)
template<int CUR>
__device__ __forceinline__ void mfma1(f32x4 (&acc)[4][2],
                                      const unsigned short* __restrict__ whf,
                                      const unsigned short* __restrict__ hbf,
                                      int nmt, int mt0, int bt0, int lane){
  #pragma unroll
  for (int kf = 0; kf < 4; ++kf){
    bf16x8 Bh0 = *(const bf16x8*)&hbf[hfr_idx(CUR, bt0+0, kf, lane, 0)];
    bf16x8 Bh1 = *(const bf16x8*)&hbf[hfr_idx(CUR, bt0+1, kf, lane, 0)];
    #pragma unroll
    for (int m = 0; m < 4; ++m){
      if (m < nmt){
        bf16x8 Ah = *(const bf16x8*)&whf[((mt0 + m)*4 + kf)*512 + lane*8];
        acc[m][0] = __builtin_amdgcn_mfma_f32_16x16x32_bf16(Ah, Bh0, acc[m][0], 0,0,0);
        acc[m][1] = __builtin_amdgcn_mfma_f32_16x16x32_bf16(Ah, Bh1, acc[m][1], 0,0,0);
      }
    }
  }
}

// init-time 3-pass: acc += Ah*Bh + Ah*Bl + Al*Bh; A = Wi hi/lo from GLOBAL (once)
__device__ __forceinline__ void mfma3_wi(f32x4 (&acc)[4][2],
                                         const unsigned short* __restrict__ frg,
                                         const unsigned short* __restrict__ hbf,
                                         int nmt, int mt0, int bt0, int lane){
  #pragma unroll
  for (int kf = 0; kf < 4; ++kf){
    bf16x8 Bh0 = *(const bf16x8*)&hbf[hfr_idx(0, bt0+0, kf, lane, 0)];
    bf16x8 Bl0 = *(const bf16x8*)&hbf[hfr_idx(1, bt0+0, kf, lane, 0)];
    bf16x8 Bh1 = *(const bf16x8*)&hbf[hfr_idx(0, bt0+1, kf, lane, 0)];
    bf16x8 Bl1 = *(const bf16x8*)&hbf[hfr_idx(1, bt0+1, kf, lane, 0)];
    #pragma unroll
    for (int m = 0; m < 4; ++m){
      if (m < nmt){
        int pidx = ((mt0 + m)*4 + kf)*64 + lane;
        bf16x8 Ah = *(const bf16x8*)(frg + WS_WI_HI + (size_t)pidx*8);
        bf16x8 Al = *(const bf16x8*)(frg + WS_WI_LO + (size_t)pidx*8);
        acc[m][0] = __builtin_amdgcn_mfma_f32_16x16x32_bf16(Ah, Bh0, acc[m][0], 0,0,0);
        acc[m][0] = __builtin_amdgcn_mfma_f32_16x16x32_bf16(Ah, Bl0, acc[m][0], 0,0,0);
        acc[m][0] = __builtin_amdgcn_mfma_f32_16x16x32_bf16(Al, Bh0, acc[m][0], 0,0,0);
        acc[m][1] = __builtin_amdgcn_mfma_f32_16x16x32_bf16(Ah, Bh1, acc[m][1], 0,0,0);
        acc[m][1] = __builtin_amdgcn_mfma_f32_16x16x32_bf16(Ah, Bl1, acc[m][1], 0,0,0);
        acc[m][1] = __builtin_amdgcn_mfma_f32_16x16x32_bf16(Al, Bh1, acc[m][1], 0,0,0);
      }
    }
  }
}

__global__ __attribute__((amdgpu_flat_work_group_size(NTHR, NTHR),
                          amdgpu_waves_per_eu(4, 4)))
void idm_sim_kernel(const float* __restrict__ sampled_z,
                    const float* __restrict__ idm_params,
                    const float* __restrict__ idm_s,
                    const float* __restrict__ sdv_acts,
                    const float* __restrict__ W1,
                    const float* __restrict__ b1,
                    const float* __restrict__ Wi,
                    const float* __restrict__ bl,
                    const float* __restrict__ Wa,
                    const float* __restrict__ ba,
                    const unsigned short* __restrict__ frg,
                    float* __restrict__ out)
{
  __shared__ __align__(16) unsigned short whf[WHF_HW];   // 102.4 KB Wh-hi frags (resident)
  __shared__ __align__(16) unsigned short hbf[HBF_HW];   // 32 KB h frags (hl = ping-pong)
  __shared__ float part_lds[2][32*64];                   // 16 KB att partials (parity dbuf)
  __shared__ float noise_lds[2][2][NB];                  // 1 KB nf/nm (parity dbuf)
  __shared__ float blp_lds[GDIM];                        // 1.6 KB permuted bl
  __shared__ float wi100p_lds[GDIM];                     // 1.6 KB permuted Wi row 100

  const int tid  = threadIdx.x;
  const int lane = tid & 63;
  const int wid  = __builtin_amdgcn_readfirstlane(tid >> 6);
  const int b0   = blockIdx.x * NB;
  const int bg   = b0 + lane;

  const int bt0 = (wid >> 3) * 2;            // btile pair {0,1} or {2,3}
  const int w8  = wid & 7;
  // roles: w8==0 -> 0 mtiles (wave0 does IDM+D; wave8 idle helper);
  //        w8 1..6 -> 4 mtiles; w8==7 -> 1 mtile + noise duty.  6*4 + 1 = 25 ✓
  const int nmt = (w8 == 0) ? 0 : ((w8 == 7) ? 1 : 4);
  const int mt0 = (w8 == 7) ? 24 : (w8 - 1)*4;
  const int lg  = lane >> 4;                 // c residue group
  const int li  = lane & 15;                 // batch-within-btile

  // ---- load Wh-hi frags to LDS (once); tables ----
  for (int i = tid; i < WHF_HW/8; i += NTHR)
    ((u32x4*)whf)[i] = ((const u32x4*)frg)[i];
  for (int i = tid; i < GDIM; i += NTHR){
    int g = i & 3, c = i >> 2;
    blp_lds[i]    = bl[g*100 + c];
    wi100p_lds[i] = Wi[(size_t)HDIM*GDIM + g*100 + c];
  }
  for (int i = tid; i < HBF_HW/8; i += NTHR)
    ((u32x4*)hbf)[i] = (u32x4)(0u);
  __syncthreads();

  // ---- proj -> h0 frags (hi in hl0, lo in hl1 for the init 3-pass) ----
  for (int idx = tid; idx < HDIM*NB; idx += NTHR){
    int k = idx >> 6;
    int b = idx & 63;
    const float* szp = sampled_z + (size_t)(b0 + b) * 6;
    float v = b1[k];
    #pragma unroll
    for (int z = 0; z < 6; ++z) v = fmaf(szp[z], W1[z*HDIM + k], v);
    unsigned short hi = f2bf(v);
    unsigned short lo = f2bf(v - bf2f(hi));
    int bt = b >> 4;
    int kf = k >> 5, lp = (b & 15) + (((k & 31) >> 3) << 4), j = k & 7;
    hbf[hfr_idx(0, bt, kf, lp, j)] = hi;
    hbf[hfr_idx(1, bt, kf, lp, j)] = lo;
  }

  // ---- per-lane init: c0 = proj for owned (c, batch); wa ----
  float wa_reg[4];
  float c_reg[4][2];
  #pragma unroll
  for (int m = 0; m < 4; ++m){
    if (m < nmt){
      int c = (mt0 + m)*4 + lg;
      wa_reg[m] = Wa[c];
      #pragma unroll
      for (int b2 = 0; b2 < 2; ++b2){
        int b = b0 + (bt0 + b2)*16 + li;
        const float* szp = sampled_z + (size_t)b * 6;
        float v = b1[c];
        #pragma unroll
        for (int z = 0; z < 6; ++z) v = fmaf(szp[z], W1[z*HDIM + c], v);
        c_reg[m][b2] = v;
      }
    }
  }
  __syncthreads();   // h0 frags (hi+lo) ready

  // ---- xzs = bl + proj @ Wi  (one-time 3-pass MFMA; Wi frags from global) ----
  float xzs[4][2][4];
  if (nmt > 0){
    f32x4 acc[4][2];
    #pragma unroll
    for (int m = 0; m < 4; ++m){
      if (m < nmt){
        int zb = (mt0 + m)*16 + lg*4;
        f32x4 blv = *(const f32x4*)&blp_lds[zb];
        acc[m][0] = blv; acc[m][1] = blv;
      }
    }
    mfma3_wi(acc, frg, hbf, nmt, mt0, bt0, lane);
    #pragma unroll
    for (int m = 0; m < 4; ++m) if (m < nmt)
      #pragma unroll
      for (int b2 = 0; b2 < 2; ++b2)
        #pragma unroll
        for (int r = 0; r < 4; ++r) xzs[m][b2][r] = acc[m][b2][r];
  }
  __syncthreads();   // everyone done with hl1 (proj-lo); it becomes ping-pong buf 1

  // ---- phase-A state (wave 0 only) ----
  float p_v0=0.f, p_tg=0.f, p_jx=0.f, p_am=0.f, p_an=0.f;
  if (wid == 0){
    const float* pp = idm_params + (size_t)bg * 5;
    p_v0 = pp[0]; p_tg = pp[1]; p_jx = pp[2]; p_am = pp[3]; p_an = pp[4];
  }
  float ego_v = 0.f, ego_x = 0.f, prev_act = 0.f;
  const float ba0 = ba[0];
  const int bb0 = b0 + bt0*16 + li;

  // One barrier per step. CUR = hbf buffer read this step (0 for even t, 1 for odd).
  // B(t) reads hbf[CUR]; C(t) writes hbf[CUR^1]; all offsets compile-time.
#define STEP_BODY(T, CURB)                                                      \
  {                                                                             \
    const int t_ = (T);                                                         \
    /* sdv loads issued early; first consumed after the MFMA (latency hidden)*/ \
    float sdv0 = 0.f, sdv1 = 0.f;                                               \
    if (nmt > 0){                                                               \
      sdv0 = sdv_acts[(size_t)bb0 * TSTEPS + t_];                               \
      sdv1 = sdv_acts[(size_t)(bb0 + 16) * TSTEPS + t_];                        \
    }                                                                           \
    float efa = 0.f, ema = 0.f, fex = 0.f, mex = 0.f;                           \
    if (wid == 0){                                                              \
      const float* sp = idm_s + ((size_t)bg * TSTEPS + t_) * 12;                \
      float4 s0 = *(const float4*)(sp);                                         \
      float4 s1 = *(const float4*)(sp + 4);                                     \
      float4 s2 = *(const float4*)(sp + 8);                                     \
      if (t_ == 0){ ego_v = s0.x; ego_x = s0.w; }                               \
      else {                                                                    \
        ego_v = ego_v + prev_act * 0.1f;                                        \
        ego_x = ego_x + ego_v * 0.1f + 0.5f * prev_act * 0.01f;                 \
      }                                                                         \
      fex = s2.z; mex = s2.w;                                                   \
      float ef_dx = (s1.x - ego_x)*fex + (1.f-fex)*s1.w;                        \
      float em_dx = (s1.y - ego_x)*mex + (1.f-mex)*s2.y;                        \
      float ef_dv = (ego_v - s0.y)*fex + (1.f-fex)*s1.z;                        \
      float em_dv = (ego_v - s0.z)*mex + (1.f-mex)*s2.x;                        \
      efa = idm_act(ego_v, ef_dv, ef_dx, p_v0, p_tg, p_jx, p_am, p_an);         \
      ema = idm_act(ego_v, em_dv, em_dx, p_v0, p_tg, p_jx, p_am, p_an);         \
    } else if (wid == 7){                                                       \
      noise_lds[CURB][0][lane] = tf_noise(KF.a, KF.b, (uint32_t)(t_*BTOT + bg));\
    } else if (wid == 15){                                                      \
      noise_lds[CURB][1][lane] = tf_noise(KM.a, KM.b, (uint32_t)(t_*BTOT + bg));\
    }                                                                           \
    /* (B) acc = xzs; acc += h @ Wh-hi  (no loaded values needed to start) */   \
    f32x4 acc[4][2];                                                            \
    if (nmt > 0){                                                               \
      _Pragma("unroll")                                                         \
      for (int m = 0; m < 4; ++m){                                              \
        if (m < nmt){                                                           \
          _Pragma("unroll")                                                     \
          for (int r = 0; r < 4; ++r){                                          \
            acc[m][0][r] = xzs[m][0][r];                                        \
            acc[m][1][r] = xzs[m][1][r];                                        \
          }                                                                     \
        }                                                                       \
      }                                                                         \
      mfma1<CURB>(acc, whf, hbf, nmt, mt0, bt0, lane);                          \
    }                                                                           \
    /* (C) z = acc + sdv*wi100; gates; write h frags to hbf[CURB^1] */          \
    float part0 = 0.f, part1 = 0.f;                                             \
    _Pragma("unroll")                                                           \
    for (int m = 0; m < 4; ++m){                                                \
      if (m < nmt){                                                             \
        int c  = (mt0 + m)*4 + lg;                                              \
        int kf = c >> 5, lp = li + (((c & 31) >> 3) << 4), j = c & 7;           \
        int zb = (mt0 + m)*16 + lg*4;                                           \
        f32x4 wiv = *(const f32x4*)&wi100p_lds[zb];                             \
        _Pragma("unroll")                                                       \
        for (int b2 = 0; b2 < 2; ++b2){                                         \
          float sdv = (b2 == 0) ? sdv0 : sdv1;                                  \
          float zi = fmaf(sdv, wiv[0], acc[m][b2][0]);                          \
          float zf = fmaf(sdv, wiv[1], acc[m][b2][1]);                          \
          float zg = fmaf(sdv, wiv[2], acc[m][b2][2]);                          \
          float zo = fmaf(sdv, wiv[3], acc[m][b2][3]);                          \
          float cn = fmaf(sigmoid_f(zf), c_reg[m][b2],                          \
                          sigmoid_f(zi) * tanh_f(zg));                          \
          c_reg[m][b2] = cn;                                                    \
          float h = sigmoid_f(zo) * tanh_f(cn);                                 \
          hbf[hfr_idx((CURB)^1, bt0 + b2, kf, lp, j)] = f2bf(h);                \
          float pw = h * wa_reg[m];                                             \
          if (b2 == 0) part0 += pw; else part1 += pw;                           \
        }                                                                       \
      }                                                                         \
    }                                                                           \
    part_lds[CURB][(wid*2 + 0)*64 + lane] = part0;                              \
    part_lds[CURB][(wid*2 + 1)*64 + lane] = part1;                              \
    __syncthreads();   /* THE barrier: hbf[CURB^1], partials, noise visible */  \
    /* (D) attention + blend (wave 0; overlaps other waves' next-step B) */     \
    if (wid == 0){                                                              \
      int half = lane >> 5;                                                     \
      int b2g  = (lane >> 4) & 1;                                               \
      int bi   = lane & 15;                                                     \
      float dot = ba0;                                                          \
      _Pragma("unroll")                                                         \
      for (int w = 0; w < 8; ++w)                                               \
        _Pragma("unroll")                                                       \
        for (int res = 0; res < 4; ++res)                                       \
          dot += part_lds[CURB][((half*8 + w)*2 + b2g)*64 + res*16 + bi];       \
      float att = sigmoid_f(5.0f * dot);                                        \
      float nf = noise_lds[CURB][0][lane];                                      \
      float nm = noise_lds[CURB][1][lane];                                      \
      float efb = fex*efa + (1.f-fex)*nf;                                       \
      float emb = mex*ema + (1.f-mex)*nm;                                       \
      float act = (1.f - att) * efb + att * emb;                                \
      prev_act = act;                                                           \
      out[(size_t)bg * TSTEPS + t_] = act;                                      \
      out[(size_t)BTOT*TSTEPS + (size_t)bg * TSTEPS + t_] = att;                \
    }                                                                           \
  }

  for (int t = 0; t < TSTEPS; t += 2){
    STEP_BODY(t,     0)
    STEP_BODY(t + 1, 1)
  }
#undef STEP_BODY
}

extern "C" void kernel_launch(void* const* d_in, const int* in_sizes, int n_in,
                              void* d_out, int out_size, void* d_ws, size_t ws_size,
                              hipStream_t stream) {
  (void)in_sizes; (void)n_in; (void)ws_size; (void)out_size;
  const float* sampled_z  = (const float*)d_in[0];
  const float* idm_params = (const float*)d_in[1];
  const float* idm_s      = (const float*)d_in[2];
  const float* sdv_acts   = (const float*)d_in[3];
  const float* W1         = (const float*)d_in[4];
  const float* b1         = (const float*)d_in[5];
  const float* Wi         = (const float*)d_in[6];
  const float* Wh         = (const float*)d_in[7];
  const float* bl         = (const float*)d_in[8];
  const float* Wa         = (const float*)d_in[9];
  const float* ba         = (const float*)d_in[10];
  float* out = (float*)d_out;                       // f32 (r5 probe)
  unsigned short* frg = (unsigned short*)d_ws;      // 307.2 KB: Wh-hi | Wi-hi | Wi-lo

  build_frags_kernel<<<25, 256, 0, stream>>>(Wi, Wh, frg);
  dim3 grid(BTOT / NB);   // 256 blocks -> 1 per CU
  dim3 block(NTHR);
  idm_sim_kernel<<<grid, block, 0, stream>>>(sampled_z, idm_params, idm_s, sdv_acts,
                                             W1, b1, Wi, bl, Wa, ba, frg, out);
}

// Round 19
// 320.099 us; speedup vs baseline: 1.6230x; 1.6230x over previous
//
#include <hip/hip_runtime.h>
#include <cstdint>
#include <cstddef>

#define BTOT   16384
#define TSTEPS 60
#define HDIM   100
#define GDIM   400
#define NB     64
#define NTHR   1024   // 16 waves

static_assert(BTOT % NB == 0, "batch tiling");

typedef __attribute__((ext_vector_type(8))) short bf16x8;
typedef __attribute__((ext_vector_type(4))) float f32x4;
typedef __attribute__((ext_vector_type(4))) unsigned int u32x4;

struct TFPair { uint32_t a, b; };

__host__ __device__ constexpr uint32_t rotl32c(uint32_t v, int r){
  return (v << r) | (v >> (32 - r));
}

// Threefry-2x32, 20 rounds, exactly as jax/_src/prng.py
__host__ __device__ constexpr TFPair tf2x32(uint32_t k0, uint32_t k1,
                                            uint32_t x0, uint32_t x1){
  const uint32_t ks2 = k0 ^ k1 ^ 0x1BD11BDAu;
  x0 += k0; x1 += k1;
  x0 += x1; x1 = rotl32c(x1,13); x1 ^= x0;
  x0 += x1; x1 = rotl32c(x1,15); x1 ^= x0;
  x0 += x1; x1 = rotl32c(x1,26); x1 ^= x0;
  x0 += x1; x1 = rotl32c(x1, 6); x1 ^= x0;
  x0 += k1;  x1 += ks2 + 1u;
  x0 += x1; x1 = rotl32c(x1,17); x1 ^= x0;
  x0 += x1; x1 = rotl32c(x1,29); x1 ^= x0;
  x0 += x1; x1 = rotl32c(x1,16); x1 ^= x0;
  x0 += x1; x1 = rotl32c(x1,24); x1 ^= x0;
  x0 += ks2; x1 += k0 + 2u;
  x0 += x1; x1 = rotl32c(x1,13); x1 ^= x0;
  x0 += x1; x1 = rotl32c(x1,15); x1 ^= x0;
  x0 += x1; x1 = rotl32c(x1,26); x1 ^= x0;
  x0 += x1; x1 = rotl32c(x1, 6); x1 ^= x0;
  x0 += k0;  x1 += k1 + 3u;
  x0 += x1; x1 = rotl32c(x1,17); x1 ^= x0;
  x0 += x1; x1 = rotl32c(x1,29); x1 ^= x0;
  x0 += x1; x1 = rotl32c(x1,16); x1 ^= x0;
  x0 += x1; x1 = rotl32c(x1,24); x1 ^= x0;
  x0 += k1;  x1 += ks2 + 4u;
  x0 += x1; x1 = rotl32c(x1,13); x1 ^= x0;
  x0 += x1; x1 = rotl32c(x1,15); x1 ^= x0;
  x0 += x1; x1 = rotl32c(x1,26); x1 ^= x0;
  x0 += x1; x1 = rotl32c(x1, 6); x1 ^= x0;
  x0 += ks2; x1 += k0 + 5u;
  return TFPair{x0, x1};
}

constexpr TFPair KF = tf2x32(0u, 42u, 0u, 0u);   // fold_in(key(42), 0)
constexpr TFPair KM = tf2x32(0u, 42u, 0u, 1u);   // fold_in(key(42), 1)

__device__ __forceinline__ float rcp_fast(float x){ return __builtin_amdgcn_rcpf(x); }
__device__ __forceinline__ float sigmoid_f(float x){ return rcp_fast(1.f + __expf(-x)); }
__device__ __forceinline__ float tanh_f(float x){
  float e = __expf(2.f * x);
  return 1.f - 2.f * rcp_fast(e + 1.f);
}

// jax.random.normal under threefry_partitionable: bits(n) = w0^w1 of tf(key,(0,n))
__device__ __forceinline__ float tf_noise(uint32_t k0, uint32_t k1, uint32_t n){
  TFPair r = tf2x32(k0, k1, 0u, n);
  uint32_t bits = r.a ^ r.b;
  float u = __uint_as_float((bits >> 9) | 0x3f800000u) - 1.0f;   // [0,1)
  const float LOV = -0.99999994f;                                // nextafter(-1,0)
  float v = fmaxf(LOV, fmaf(u, 2.0f, LOV));
  float w = -log1pf(-v * v);
  float p;
  if (w < 5.0f){
    w -= 2.5f;
    p =              2.81022636e-08f;
    p = fmaf(p, w,   3.43273939e-07f);
    p = fmaf(p, w,  -3.5233877e-06f);
    p = fmaf(p, w,  -4.39150654e-06f);
    p = fmaf(p, w,   0.00021858087f);
    p = fmaf(p, w,  -0.00125372503f);
    p = fmaf(p, w,  -0.00417768164f);
    p = fmaf(p, w,   0.246640727f);
    p = fmaf(p, w,   1.50140941f);
  } else {
    w = sqrtf(w) - 3.0f;
    p =             -0.000200214257f;
    p = fmaf(p, w,   0.000100950558f);
    p = fmaf(p, w,   0.00134934322f);
    p = fmaf(p, w,  -0.00367342844f);
    p = fmaf(p, w,   0.00573950773f);
    p = fmaf(p, w,  -0.0076224613f);
    p = fmaf(p, w,   0.00943887047f);
    p = fmaf(p, w,   1.00167406f);
    p = fmaf(p, w,   2.83297682f);
  }
  return 0.70710678f * (p * v);
}

__device__ __forceinline__ float idm_act(float vel, float dv, float dx,
                                         float v0, float tg, float jx,
                                         float am, float an){
  dx = fminf(fmaxf(dx, 0.5f), 1000.0f);
  float gap = jx + fmaxf(0.0f, tg*vel + vel*dv / (2.0f * sqrtf(am*an)));
  float r  = vel / v0;  float r2 = r*r;
  float gd = gap / dx;
  float a  = am * (1.0f - r2*r2 - gd*gd);
  return fminf(fmaxf(a, -3.0f), 3.0f);
}

// ---- bf16 split helpers (RNE) ----
__device__ __forceinline__ unsigned short f2bf(float f){
  uint32_t x = __float_as_uint(f);
  return (unsigned short)((x + 0x7fffu + ((x >> 16) & 1u)) >> 16);
}
__device__ __forceinline__ float bf2f(unsigned short h){
  return __uint_as_float(((uint32_t)h) << 16);
}

// Permuted z column zp = c*4 + gate <-> orig = gate*100 + c.  K = 128 (4 kf), k>=100 zero.
// A-frag (16x16x32): packet p = (mt*4 + kf)*64 + lane; lane l -> zrow = mt*16 + (l&15),
// k = kf*32 + (l>>4)*8 + j.
// ws halfword layout: [0,51200) Wh-hi   [51200,102400) Wi-hi   [102400,153600) Wi-lo
#define FRG_PACKETS (25*4*64)     // 6400
#define WS_WI_HI 51200
#define WS_WI_LO 102400
#define WHF_HW   51200            // Wh-hi frags: 102.4 KB

__global__ void build_frags_kernel(const float* __restrict__ Wi,
                                   const float* __restrict__ Wh,
                                   unsigned short* __restrict__ ws){
  int p = blockIdx.x * 256 + threadIdx.x;
  if (p >= FRG_PACKETS) return;
  int lane = p & 63;
  int kf   = (p >> 6) & 3;
  int mt   = p >> 8;
  int zc   = mt*16 + (lane & 15);             // permuted column
  int orig = (zc & 3)*100 + (zc >> 2);        // gate*100 + c
  int kb   = kf*32 + ((lane >> 4) << 3);
  #pragma unroll
  for (int j = 0; j < 8; ++j){
    int k = kb + j;
    float vh = (k < HDIM) ? Wh[(size_t)k*GDIM + orig] : 0.f;
    float vi = (k < HDIM) ? Wi[(size_t)k*GDIM + orig] : 0.f;
    unsigned short ih = f2bf(vi);
    ws[p*8 + j]            = f2bf(vh);               // Wh-hi (lo dropped: 2-pass)
    ws[WS_WI_HI + p*8 + j] = ih;                     // Wi-hi
    ws[WS_WI_LO + p*8 + j] = f2bf(vi - bf2f(ih));    // Wi-lo
  }
}

// h-frag LDS: one frag = 512 hw; flat idx
#define HBF_HW (2*4*4*512)   // 16384 hw = 32 KB, single buffer
__device__ __forceinline__ int hfr_idx(int hl, int bt, int kf, int lp, int j){
  return (((hl*4 + bt)*4 + kf)*512 + lp*8 + j);
}

// steady-state 2-pass: acc += Whi*(Bh + Bl), A from LDS, B from LDS
__device__ __forceinline__ void mfma2(f32x4 (&acc)[4][2],
                                      const unsigned short* __restrict__ whf,
                                      const unsigned short* __restrict__ hbf,
                                      int nmt, int mt0, int bt0, int lane){
  #pragma unroll
  for (int kf = 0; kf < 4; ++kf){
    bf16x8 Bh0 = *(const bf16x8*)&hbf[hfr_idx(0, bt0+0, kf, lane, 0)];
    bf16x8 Bl0 = *(const bf16x8*)&hbf[hfr_idx(1, bt0+0, kf, lane, 0)];
    bf16x8 Bh1 = *(const bf16x8*)&hbf[hfr_idx(0, bt0+1, kf, lane, 0)];
    bf16x8 Bl1 = *(const bf16x8*)&hbf[hfr_idx(1, bt0+1, kf, lane, 0)];
    #pragma unroll
    for (int m = 0; m < 4; ++m){
      if (m < nmt){
        bf16x8 Ah = *(const bf16x8*)&whf[((mt0 + m)*4 + kf)*512 + lane*8];
        acc[m][0] = __builtin_amdgcn_mfma_f32_16x16x32_bf16(Ah, Bh0, acc[m][0], 0,0,0);
        acc[m][0] = __builtin_amdgcn_mfma_f32_16x16x32_bf16(Ah, Bl0, acc[m][0], 0,0,0);
        acc[m][1] = __builtin_amdgcn_mfma_f32_16x16x32_bf16(Ah, Bh1, acc[m][1], 0,0,0);
        acc[m][1] = __builtin_amdgcn_mfma_f32_16x16x32_bf16(Ah, Bl1, acc[m][1], 0,0,0);
      }
    }
  }
}

// init-time 3-pass: acc += Ah*Bh + Ah*Bl + Al*Bh, A = Wi hi/lo from GLOBAL (once)
__device__ __forceinline__ void mfma3_wi(f32x4 (&acc)[4][2],
                                         const unsigned short* __restrict__ frg,
                                         const unsigned short* __restrict__ hbf,
                                         int nmt, int mt0, int bt0, int lane){
  #pragma unroll
  for (int kf = 0; kf < 4; ++kf){
    bf16x8 Bh0 = *(const bf16x8*)&hbf[hfr_idx(0, bt0+0, kf, lane, 0)];
    bf16x8 Bl0 = *(const bf16x8*)&hbf[hfr_idx(1, bt0+0, kf, lane, 0)];
    bf16x8 Bh1 = *(const bf16x8*)&hbf[hfr_idx(0, bt0+1, kf, lane, 0)];
    bf16x8 Bl1 = *(const bf16x8*)&hbf[hfr_idx(1, bt0+1, kf, lane, 0)];
    #pragma unroll
    for (int m = 0; m < 4; ++m){
      if (m < nmt){
        int pidx = ((mt0 + m)*4 + kf)*64 + lane;
        bf16x8 Ah = *(const bf16x8*)(frg + WS_WI_HI + (size_t)pidx*8);
        bf16x8 Al = *(const bf16x8*)(frg + WS_WI_LO + (size_t)pidx*8);
        acc[m][0] = __builtin_amdgcn_mfma_f32_16x16x32_bf16(Ah, Bh0, acc[m][0], 0,0,0);
        acc[m][0] = __builtin_amdgcn_mfma_f32_16x16x32_bf16(Ah, Bl0, acc[m][0], 0,0,0);
        acc[m][0] = __builtin_amdgcn_mfma_f32_16x16x32_bf16(Al, Bh0, acc[m][0], 0,0,0);
        acc[m][1] = __builtin_amdgcn_mfma_f32_16x16x32_bf16(Ah, Bh1, acc[m][1], 0,0,0);
        acc[m][1] = __builtin_amdgcn_mfma_f32_16x16x32_bf16(Ah, Bl1, acc[m][1], 0,0,0);
        acc[m][1] = __builtin_amdgcn_mfma_f32_16x16x32_bf16(Al, Bh1, acc[m][1], 0,0,0);
      }
    }
  }
}

__global__ __attribute__((amdgpu_flat_work_group_size(NTHR, NTHR),
                          amdgpu_waves_per_eu(4, 4)))
void idm_sim_kernel(const float* __restrict__ sampled_z,
                    const float* __restrict__ idm_params,
                    const float* __restrict__ idm_s,
                    const float* __restrict__ sdv_acts,
                    const float* __restrict__ W1,
                    const float* __restrict__ b1,
                    const float* __restrict__ Wi,
                    const float* __restrict__ bl,
                    const float* __restrict__ Wa,
                    const float* __restrict__ ba,
                    const unsigned short* __restrict__ frg,
                    float* __restrict__ out)
{
  __shared__ __align__(16) unsigned short whf[WHF_HW];   // 102.4 KB Wh-hi frags (resident)
  __shared__ __align__(16) unsigned short hbf[HBF_HW];   // 32 KB h frags hi/lo (single buf)
  __shared__ float part_lds[32*64];                      // 8 KB att partials
  __shared__ float noise_lds[2][2][NB];                  // 1 KB nf/nm (dbuf by t&1)
  __shared__ float blp_lds[GDIM];                        // 1.6 KB permuted bl
  __shared__ float wi100p_lds[GDIM];                     // 1.6 KB permuted Wi row 100

  const int tid  = threadIdx.x;
  const int lane = tid & 63;
  const int wid  = __builtin_amdgcn_readfirstlane(tid >> 6);
  const int b0   = blockIdx.x * NB;
  const int bg   = b0 + lane;

  const int bt0 = (wid >> 3) * 2;            // btile pair {0,1} or {2,3}
  const int w8  = wid & 7;
  const int nmt = (w8 == 7) ? 4 : 3;         // 7*3 + 4 = 25 mtiles
  const int mt0 = w8 * 3;
  const int lg  = lane >> 4;                 // c residue group
  const int li  = lane & 15;                 // batch-within-btile

  // ---- load Wh-hi frags to LDS (once); zero h buffer; tables ----
  for (int i = tid; i < WHF_HW/8; i += NTHR)
    ((u32x4*)whf)[i] = ((const u32x4*)frg)[i];
  for (int i = tid; i < HBF_HW/8; i += NTHR)
    ((u32x4*)hbf)[i] = (u32x4)(0u);
  for (int i = tid; i < GDIM; i += NTHR){
    int g = i & 3, c = i >> 2;
    blp_lds[i]    = bl[g*100 + c];
    wi100p_lds[i] = Wi[(size_t)HDIM*GDIM + g*100 + c];
  }
  __syncthreads();

  // ---- proj -> h0 frags (k = c, 0..99) ----
  for (int idx = tid; idx < HDIM*NB; idx += NTHR){
    int k = idx >> 6;
    int b = idx & 63;
    const float* szp = sampled_z + (size_t)(b0 + b) * 6;
    float v = b1[k];
    #pragma unroll
    for (int z = 0; z < 6; ++z) v = fmaf(szp[z], W1[z*HDIM + k], v);
    unsigned short hi = f2bf(v);
    unsigned short lo = f2bf(v - bf2f(hi));
    int bt = b >> 4;
    int kf = k >> 5, lp = (b & 15) + (((k & 31) >> 3) << 4), j = k & 7;
    hbf[hfr_idx(0, bt, kf, lp, j)] = hi;
    hbf[hfr_idx(1, bt, kf, lp, j)] = lo;
  }

  // ---- per-lane init: c0 = proj for owned (c, batch); wa ----
  float wa_reg[4];
  float c_reg[4][2];
  #pragma unroll
  for (int m = 0; m < 4; ++m){
    if (m < nmt){
      int c = (mt0 + m)*4 + lg;
      wa_reg[m] = Wa[c];
      #pragma unroll
      for (int b2 = 0; b2 < 2; ++b2){
        int b = b0 + (bt0 + b2)*16 + li;
        const float* szp = sampled_z + (size_t)b * 6;
        float v = b1[c];
        #pragma unroll
        for (int z = 0; z < 6; ++z) v = fmaf(szp[z], W1[z*HDIM + c], v);
        c_reg[m][b2] = v;
      }
    }
  }
  __syncthreads();   // h0 frags ready

  // ---- xzs = bl + proj @ Wi  (one-time 3-pass MFMA; Wi frags from global) ----
  float xzs[4][2][4];
  {
    f32x4 acc[4][2];
    #pragma unroll
    for (int m = 0; m < 4; ++m){
      if (m < nmt){
        int zb = (mt0 + m)*16 + lg*4;
        f32x4 blv = *(const f32x4*)&blp_lds[zb];
        acc[m][0] = blv; acc[m][1] = blv;
      }
    }
    mfma3_wi(acc, frg, hbf, nmt, mt0, bt0, lane);
    #pragma unroll
    for (int m = 0; m < 4; ++m) if (m < nmt)
      #pragma unroll
      for (int b2 = 0; b2 < 2; ++b2)
        #pragma unroll
        for (int r = 0; r < 4; ++r) xzs[m][b2][r] = acc[m][b2][r];
  }

  // ---- phase-A state (wave 0 only) ----
  float p_v0=0.f, p_tg=0.f, p_jx=0.f, p_am=0.f, p_an=0.f;
  if (wid == 0){
    const float* pp = idm_params + (size_t)bg * 5;
    p_v0 = pp[0]; p_tg = pp[1]; p_jx = pp[2]; p_am = pp[3]; p_an = pp[4];
  }
  float ego_v = 0.f, ego_x = 0.f, prev_act = 0.f;
  const float ba0 = ba[0];
  const int bb0 = b0 + bt0*16 + li;

  for (int t = 0; t < TSTEPS; ++t){
    float efa = 0.f, ema = 0.f, fex = 0.f, mex = 0.f;
    // ---- (A) wave0: ego/IDM; waves 1,2: noise (dbuf by parity) ----
    if (wid == 0){
      const float* sp = idm_s + ((size_t)bg * TSTEPS + t) * 12;
      float4 s0 = *(const float4*)(sp);
      float4 s1 = *(const float4*)(sp + 4);
      float4 s2 = *(const float4*)(sp + 8);
      if (t == 0){ ego_v = s0.x; ego_x = s0.w; }
      else {
        ego_v = ego_v + prev_act * 0.1f;
        ego_x = ego_x + ego_v * 0.1f + 0.5f * prev_act * 0.01f;
      }
      fex = s2.z; mex = s2.w;
      float ef_dx = (s1.x - ego_x)*fex + (1.f-fex)*s1.w;
      float em_dx = (s1.y - ego_x)*mex + (1.f-mex)*s2.y;
      float ef_dv = (ego_v - s0.y)*fex + (1.f-fex)*s1.z;
      float em_dv = (ego_v - s0.z)*mex + (1.f-mex)*s2.x;
      efa = idm_act(ego_v, ef_dv, ef_dx, p_v0, p_tg, p_jx, p_am, p_an);
      ema = idm_act(ego_v, em_dv, em_dx, p_v0, p_tg, p_jx, p_am, p_an);
    } else if (wid == 1){
      noise_lds[t & 1][0][lane] = tf_noise(KF.a, KF.b, (uint32_t)(t*BTOT + bg));
    } else if (wid == 2){
      noise_lds[t & 1][1][lane] = tf_noise(KM.a, KM.b, (uint32_t)(t*BTOT + bg));
    }

    // ---- (B) z = xzs + sdv*wi100 + h @ Wh-hi (2-pass, all-LDS operands) ----
    float sdv0 = sdv_acts[(size_t)bb0 * TSTEPS + t];
    float sdv1 = sdv_acts[(size_t)(bb0 + 16) * TSTEPS + t];
    f32x4 acc[4][2];
    #pragma unroll
    for (int m = 0; m < 4; ++m){
      if (m < nmt){
        int zb = (mt0 + m)*16 + lg*4;
        f32x4 wiv = *(const f32x4*)&wi100p_lds[zb];
        #pragma unroll
        for (int r = 0; r < 4; ++r){
          acc[m][0][r] = fmaf(sdv0, wiv[r], xzs[m][0][r]);
          acc[m][1][r] = fmaf(sdv1, wiv[r], xzs[m][1][r]);
        }
      }
    }
    mfma2(acc, whf, hbf, nmt, mt0, bt0, lane);
    __syncthreads();   // bar1: all reads of hbf done; safe to overwrite

    // ---- (C) gates + cell/hidden update in registers; write new h frags ----
    float part0 = 0.f, part1 = 0.f;
    #pragma unroll
    for (int m = 0; m < 4; ++m){
      if (m < nmt){
        int c  = (mt0 + m)*4 + lg;
        int kf = c >> 5, lp = li + (((c & 31) >> 3) << 4), j = c & 7;
        #pragma unroll
        for (int b2 = 0; b2 < 2; ++b2){
          float zi = acc[m][b2][0];
          float zf = acc[m][b2][1];
          float zg = acc[m][b2][2];
          float zo = acc[m][b2][3];
          float cn = fmaf(sigmoid_f(zf), c_reg[m][b2], sigmoid_f(zi) * tanh_f(zg));
          c_reg[m][b2] = cn;
          float h = sigmoid_f(zo) * tanh_f(cn);
          unsigned short hh_ = f2bf(h);
          unsigned short hl_ = f2bf(h - bf2f(hh_));
          hbf[hfr_idx(0, bt0 + b2, kf, lp, j)] = hh_;
          hbf[hfr_idx(1, bt0 + b2, kf, lp, j)] = hl_;
          float pw = h * wa_reg[m];
          if (b2 == 0) part0 += pw; else part1 += pw;
        }
      }
    }
    part_lds[(wid*2 + 0)*64 + lane] = part0;
    part_lds[(wid*2 + 1)*64 + lane] = part1;
    __syncthreads();   // bar2: new h, partials, this step's noise visible

    // ---- (D) attention + blended action (wave 0 only) ----
    if (wid == 0){
      int half = lane >> 5;
      int b2g  = (lane >> 4) & 1;
      int bi   = lane & 15;
      float dot = ba0;
      #pragma unroll
      for (int w = 0; w < 8; ++w)
        #pragma unroll
        for (int res = 0; res < 4; ++res)
          dot += part_lds[((half*8 + w)*2 + b2g)*64 + res*16 + bi];
      float att = sigmoid_f(5.0f * dot);
      float nf = noise_lds[t & 1][0][lane];
      float nm = noise_lds[t & 1][1][lane];
      float efb = fex*efa + (1.f-fex)*nf;
      float emb = mex*ema + (1.f-mex)*nm;
      float act = (1.f - att) * efb + att * emb;
      prev_act = act;
      out[(size_t)bg * TSTEPS + t] = act;
      out[(size_t)BTOT*TSTEPS + (size_t)bg * TSTEPS + t] = att;
    }
  }
}

extern "C" void kernel_launch(void* const* d_in, const int* in_sizes, int n_in,
                              void* d_out, int out_size, void* d_ws, size_t ws_size,
                              hipStream_t stream) {
  (void)in_sizes; (void)n_in; (void)ws_size; (void)out_size;
  const float* sampled_z  = (const float*)d_in[0];
  const float* idm_params = (const float*)d_in[1];
  const float* idm_s      = (const float*)d_in[2];
  const float* sdv_acts   = (const float*)d_in[3];
  const float* W1         = (const float*)d_in[4];
  const float* b1         = (const float*)d_in[5];
  const float* Wi         = (const float*)d_in[6];
  const float* Wh         = (const float*)d_in[7];
  const float* bl         = (const float*)d_in[8];
  const float* Wa         = (const float*)d_in[9];
  const float* ba         = (const float*)d_in[10];
  float* out = (float*)d_out;                       // f32 (r5 probe)
  unsigned short* frg = (unsigned short*)d_ws;      // 307.2 KB: Wh-hi | Wi-hi | Wi-lo

  build_frags_kernel<<<25, 256, 0, stream>>>(Wi, Wh, frg);
  dim3 grid(BTOT / NB);   // 256 blocks -> 1 per CU
  dim3 block(NTHR);
  idm_sim_kernel<<<grid, block, 0, stream>>>(sampled_z, idm_params, idm_s, sdv_acts,
                                             W1, b1, Wi, bl, Wa, ba, frg, out);
}